// Round 4
// baseline (572.880 us; speedup 1.0000x reference)
//
#include <hip/hip_runtime.h>
#include <stdint.h>
#include <stddef.h>

#define M_DIM 8192
#define N_DIM 4096
#define K_DIM 4096

#define BM 128
#define BN 128
#define BK 64

typedef __bf16 bf16x8 __attribute__((ext_vector_type(8)));
typedef float f32x4 __attribute__((ext_vector_type(4)));

__device__ __forceinline__ void async_load16(void* lds, const void* g) {
  __builtin_amdgcn_global_load_lds(
      (const __attribute__((address_space(1))) void*)g,
      (__attribute__((address_space(3))) void*)lds,
      16, 0, 0);
}

// W int32 -> bf16. Exact: |q|<=127 fits bf16's 8-bit mantissa under any rounding.
__global__ void cvt_w_kernel(const int* __restrict__ w, __bf16* __restrict__ y) {
  size_t i = ((size_t)blockIdx.x * blockDim.x + threadIdx.x) * 8;
  const int4* p = (const int4*)(w + i);
  int4 a = p[0], b = p[1];
  bf16x8 o;
  o[0] = (__bf16)(float)a.x; o[1] = (__bf16)(float)a.y;
  o[2] = (__bf16)(float)a.z; o[3] = (__bf16)(float)a.w;
  o[4] = (__bf16)(float)b.x; o[5] = (__bf16)(float)b.y;
  o[6] = (__bf16)(float)b.z; o[7] = (__bf16)(float)b.w;
  *(bf16x8*)(y + i) = o;
}

// C[M,N] = A[M,K](fp32) * B[N,K](bf16)^T, scaled per column n by scaler[n].
// A staged RAW fp32 via global_load_lds (32 KiB), converted to bf16 at
// fragment read. B staged bf16 (16 KiB). 128x128 tile, BK=64, 4 waves.
// Grid is 1D; block->tile mapping is XCD-grouped (see kernel_launch comment).
__global__ __launch_bounds__(256, 2) void gemm_fused(
    const float* __restrict__ A, const __bf16* __restrict__ B,
    const float* __restrict__ scaler, float* __restrict__ C) {
  __shared__ __align__(16) uint8_t sA[BM * BK * 4];  // 32 KiB fp32
  __shared__ __align__(16) uint8_t sB[BN * BK * 2];  // 16 KiB bf16

  // XCD-grouped swizzle. Hardware round-robins blocks: xcd = bid % 8.
  // Each XCD owns 4 consecutive n-tiles (4 x 1 MB B K-slabs -> L2-resident);
  // all XCDs sweep the same m-tile window concurrently, so each 2 MB fp32
  // A-slice is fetched from HBM once and L3-served to all 8 XCDs.
  const int bid  = blockIdx.x;          // 0..2047
  const int xcd  = bid & 7;
  const int slot = bid >> 3;            // 0..255 per XCD
  const int tile_n = (xcd * 4 + (slot & 3)) * BN;  // n-tile 0..31
  const int tile_m = (slot >> 2) * BM;             // m-tile 0..63

  const int w    = threadIdx.x >> 6;
  const int lane = threadIdx.x & 63;
  const int q    = lane >> 4;      // quad 0..3
  const int m16  = lane & 15;
  const int wrow = (w >> 1) * 64;  // wave's 64x64 patch
  const int wcol = (w & 1) * 64;

  f32x4 acc[4][4];
#pragma unroll
  for (int i = 0; i < 4; ++i)
#pragma unroll
    for (int j = 0; j < 4; ++j)
      acc[i][j] = (f32x4){0.f, 0.f, 0.f, 0.f};

  for (int kt = 0; kt < K_DIM; kt += BK) {
    // A: 128 rows x 16 chunks(16B = 4 fp32) = 2048 chunks, 8 rounds.
    // Slot g holds (r = g>>4, c = (g&15) ^ (r&15)).
    // lds addr = wave-uniform base + lane*16 (global_load_lds constraint).
#pragma unroll
    for (int p = 0; p < 8; ++p) {
      int g = ((p * 4 + w) << 6) + lane;
      int r = g >> 4;
      int c = (g & 15) ^ (r & 15);
      async_load16(sA + (size_t)g * 16,
                   A + (size_t)(tile_m + r) * K_DIM + kt + c * 4);
    }
    // B: 128 rows x 8 chunks(16B = 8 bf16) = 1024 chunks, 4 rounds.
#pragma unroll
    for (int p = 0; p < 4; ++p) {
      int g = ((p * 4 + w) << 6) + lane;
      int r = g >> 3;
      int c = (g & 7) ^ (r & 7);
      async_load16(sB + (size_t)g * 16,
                   B + (size_t)(tile_n + r) * K_DIM + kt + c * 8);
    }
    __syncthreads();

#pragma unroll
    for (int ks = 0; ks < 2; ++ks) {
      const int ka = (ks << 2) + q;  // 8-elem K group index, 0..7
      bf16x8 af[4], bfr[4];
#pragma unroll
      for (int t = 0; t < 4; ++t) {
        // A fragment: row ra, K elems [ka*8, ka*8+8) = chunks 2ka, 2ka+1.
        int ra = wrow + t * 16 + m16;
        int s0 = (ra << 4) + ((2 * ka) ^ (ra & 15));
        int s1 = (ra << 4) + ((2 * ka + 1) ^ (ra & 15));
        f32x4 a0 = *(const f32x4*)(sA + (size_t)s0 * 16);
        f32x4 a1 = *(const f32x4*)(sA + (size_t)s1 * 16);
        bf16x8 v;
        v[0] = (__bf16)a0[0]; v[1] = (__bf16)a0[1];
        v[2] = (__bf16)a0[2]; v[3] = (__bf16)a0[3];
        v[4] = (__bf16)a1[0]; v[5] = (__bf16)a1[1];
        v[6] = (__bf16)a1[2]; v[7] = (__bf16)a1[3];
        af[t] = v;
        int rb = wcol + t * 16 + m16;
        bfr[t] = *(const bf16x8*)(sB + (size_t)(((rb << 3) + (ka ^ (rb & 7))) << 4));
      }
#pragma unroll
      for (int i = 0; i < 4; ++i)
#pragma unroll
        for (int j = 0; j < 4; ++j)
          acc[i][j] = __builtin_amdgcn_mfma_f32_16x16x32_bf16(
              af[i], bfr[j], acc[i][j], 0, 0, 0);
    }
    __syncthreads();
  }

  // Epilogue: C/D layout col=lane&15, row=(lane>>4)*4+reg. Scale by scaler[col].
#pragma unroll
  for (int j = 0; j < 4; ++j) {
    int col = tile_n + wcol + j * 16 + m16;
    float s = scaler[col];
#pragma unroll
    for (int i = 0; i < 4; ++i) {
      int row0 = tile_m + wrow + i * 16 + q * 4;
#pragma unroll
      for (int r = 0; r < 4; ++r)
        C[(size_t)(row0 + r) * N_DIM + col] = acc[i][j][r] * s;
    }
  }
}

// Correct-but-slow insurance if ws_size can't hold the bf16 weight copy.
__global__ void fallback_kernel(const float* __restrict__ x,
                                const int* __restrict__ wq,
                                const float* __restrict__ s,
                                float* __restrict__ out) {
  size_t idx = (size_t)blockIdx.x * blockDim.x + threadIdx.x;
  int m = (int)(idx / N_DIM), n = (int)(idx % N_DIM);
  const float* xr = x + (size_t)m * K_DIM;
  const int* wr = wq + (size_t)n * K_DIM;
  float acc = 0.f;
  for (int k = 0; k < K_DIM; ++k) acc += xr[k] * (float)wr[k];
  out[idx] = acc * s[n];
}

extern "C" void kernel_launch(void* const* d_in, const int* in_sizes, int n_in,
                              void* d_out, int out_size, void* d_ws, size_t ws_size,
                              hipStream_t stream) {
  const float* x = (const float*)d_in[0];
  const int* wq = (const int*)d_in[1];   // int32 per harness contract (verified R2)
  const float* sc = (const float*)d_in[2];
  float* out = (float*)d_out;

  const size_t nw = (size_t)N_DIM * K_DIM;            // 16,777,216
  const size_t need = nw * sizeof(uint16_t);          // ~33.6 MB

  if (ws_size < need) {
    size_t total = (size_t)M_DIM * N_DIM;
    fallback_kernel<<<(int)(total / 256), 256, 0, stream>>>(x, wq, sc, out);
    return;
  }

  __bf16* Wb = (__bf16*)d_ws;
  cvt_w_kernel<<<(int)(nw / 8 / 256), 256, 0, stream>>>(wq, Wb);

  // 1D grid, XCD-grouped mapping inside the kernel.
  gemm_fused<<<(N_DIM / BN) * (M_DIM / BM), 256, 0, stream>>>(x, Wb, sc, out);
}

// Round 5
// 390.346 us; speedup vs baseline: 1.4676x; 1.4676x over previous
//
#include <hip/hip_runtime.h>
#include <stdint.h>
#include <stddef.h>

#define M_DIM 8192
#define N_DIM 4096
#define K_DIM 4096

#define BM 128
#define BN 128
#define BK 128   // int8: 128 rows x 128 bytes = 16 KiB per operand tile

typedef int i32x4 __attribute__((ext_vector_type(4)));

__device__ __forceinline__ void async_load16(void* lds, const void* g) {
  __builtin_amdgcn_global_load_lds(
      (const __attribute__((address_space(1))) void*)g,
      (__attribute__((address_space(3))) void*)lds,
      16, 0, 0);
}

// Per-token (row) symmetric int8 quantization of x.
// One block per row of 4096 fp32. s_r = rowmax/127; xq = rint(x/s_r).
__global__ void quant_x_kernel(const float* __restrict__ x,
                               signed char* __restrict__ xq,
                               float* __restrict__ xs) {
  const int row = blockIdx.x;
  const float* xr = x + (size_t)row * K_DIM;
  const int t = threadIdx.x;
  float4 v[4];
  float m = 0.f;
#pragma unroll
  for (int r = 0; r < 4; ++r) {
    v[r] = *(const float4*)(xr + t * 16 + r * 4);
    m = fmaxf(m, fmaxf(fmaxf(fabsf(v[r].x), fabsf(v[r].y)),
                       fmaxf(fabsf(v[r].z), fabsf(v[r].w))));
  }
#pragma unroll
  for (int off = 32; off > 0; off >>= 1)
    m = fmaxf(m, __shfl_down(m, off, 64));
  __shared__ float wmax[4];
  if ((t & 63) == 0) wmax[t >> 6] = m;
  __syncthreads();
  float rowmax = fmaxf(fmaxf(wmax[0], wmax[1]), fmaxf(wmax[2], wmax[3]));
  float inv = rowmax > 0.f ? 127.0f / rowmax : 0.f;
  if (t == 0) xs[row] = rowmax > 0.f ? rowmax * (1.0f / 127.0f) : 0.f;
  union { signed char c[16]; uint4 u; } o;
#pragma unroll
  for (int r = 0; r < 4; ++r) {
    o.c[r * 4 + 0] = (signed char)(int)rintf(v[r].x * inv);
    o.c[r * 4 + 1] = (signed char)(int)rintf(v[r].y * inv);
    o.c[r * 4 + 2] = (signed char)(int)rintf(v[r].z * inv);
    o.c[r * 4 + 3] = (signed char)(int)rintf(v[r].w * inv);
  }
  *(uint4*)(xq + (size_t)row * K_DIM + t * 16) = o.u;
}

// W int32 [-127,127] -> int8 (exact pack). 16 elems/thread.
__global__ void pack_w_kernel(const int* __restrict__ w, signed char* __restrict__ wp) {
  size_t i = ((size_t)blockIdx.x * blockDim.x + threadIdx.x) * 16;
  union { signed char c[16]; uint4 u; } o;
#pragma unroll
  for (int r = 0; r < 4; ++r) {
    int4 a = *(const int4*)(w + i + r * 4);
    o.c[r * 4 + 0] = (signed char)a.x; o.c[r * 4 + 1] = (signed char)a.y;
    o.c[r * 4 + 2] = (signed char)a.z; o.c[r * 4 + 3] = (signed char)a.w;
  }
  *(uint4*)(wp + i) = o.u;
}

// C[M,N] = sum_k Aq[m,k]*Bq[n,k] * xs[m] * scaler[n], int8 MFMA 16x16x64.
// Aq,Bq int8 K-contiguous. 128x128 tile, BK=128, 4 waves (2x2 of 64x64).
// Both operands: 128 rows x 8 chunks(16B), XOR chunk swizzle (measured 0
// conflicts R2-R4 with identical geometry). A/B frag: 16 consecutive int8
// per lane, k=(lane>>4)*16+j (extrapolated from m89-verified bf16 pattern;
// identical 4-VGPR register shape). C/D layout dtype-independent (m121-m128).
__global__ __launch_bounds__(256, 2) void gemm_i8(
    const signed char* __restrict__ Aq, const signed char* __restrict__ Bq,
    const float* __restrict__ xs, const float* __restrict__ scaler,
    float* __restrict__ C) {
  __shared__ __align__(16) uint8_t sA[BM * BK];  // 16 KiB
  __shared__ __align__(16) uint8_t sB[BN * BK];  // 16 KiB

  // XCD-grouped mapping (neutral R4, harmless; keeps B slabs L2-resident).
  const int bid  = blockIdx.x;
  const int xcd  = bid & 7;
  const int slot = bid >> 3;
  const int tile_n = (xcd * 4 + (slot & 3)) * BN;
  const int tile_m = (slot >> 2) * BM;

  const int w    = threadIdx.x >> 6;
  const int lane = threadIdx.x & 63;
  const int q    = lane >> 4;
  const int m16  = lane & 15;
  const int wrow = (w >> 1) * 64;
  const int wcol = (w & 1) * 64;

  i32x4 acc[4][4];
#pragma unroll
  for (int i = 0; i < 4; ++i)
#pragma unroll
    for (int j = 0; j < 4; ++j)
      acc[i][j] = (i32x4){0, 0, 0, 0};

  for (int kt = 0; kt < K_DIM; kt += BK) {
    // Stage A and B: 1024 16B-chunks each, 4 rounds x 4 waves x 64 lanes.
    // Slot g holds (r = g>>3, c = (g&7) ^ (r&7)); lds addr = wave-uniform
    // base + lane*16 (global_load_lds constraint).
#pragma unroll
    for (int p = 0; p < 4; ++p) {
      int g = ((p * 4 + w) << 6) + lane;
      int r = g >> 3;
      int c = (g & 7) ^ (r & 7);
      async_load16(sA + (size_t)g * 16,
                   Aq + (size_t)(tile_m + r) * K_DIM + kt + c * 16);
    }
#pragma unroll
    for (int p = 0; p < 4; ++p) {
      int g = ((p * 4 + w) << 6) + lane;
      int r = g >> 3;
      int c = (g & 7) ^ (r & 7);
      async_load16(sB + (size_t)g * 16,
                   Bq + (size_t)(tile_n + r) * K_DIM + kt + c * 16);
    }
    __syncthreads();

#pragma unroll
    for (int ks = 0; ks < 2; ++ks) {
      const int ck = (ks << 2) + q;   // chunk index 0..7 = K bytes [ck*16, +16)
      i32x4 af[4], bfr[4];
#pragma unroll
      for (int t = 0; t < 4; ++t) {
        int ra = wrow + t * 16 + m16;
        af[t] = *(const i32x4*)(sA + (size_t)(((ra << 3) + (ck ^ (ra & 7))) << 4));
        int rb = wcol + t * 16 + m16;
        bfr[t] = *(const i32x4*)(sB + (size_t)(((rb << 3) + (ck ^ (rb & 7))) << 4));
      }
#pragma unroll
      for (int i = 0; i < 4; ++i)
#pragma unroll
        for (int j = 0; j < 4; ++j)
          acc[i][j] = __builtin_amdgcn_mfma_i32_16x16x64_i8(
              af[i], bfr[j], acc[i][j], 0, 0, 0);
    }
    __syncthreads();
  }

  // Epilogue: C/D col=lane&15, row=(lane>>4)*4+reg (verified layout).
  float rs[4][4];
#pragma unroll
  for (int i = 0; i < 4; ++i)
#pragma unroll
    for (int r = 0; r < 4; ++r)
      rs[i][r] = xs[tile_m + wrow + i * 16 + q * 4 + r];
#pragma unroll
  for (int j = 0; j < 4; ++j) {
    int col = tile_n + wcol + j * 16 + m16;
    float s = scaler[col];
#pragma unroll
    for (int i = 0; i < 4; ++i) {
      int row0 = tile_m + wrow + i * 16 + q * 4;
#pragma unroll
      for (int r = 0; r < 4; ++r)
        C[(size_t)(row0 + r) * N_DIM + col] = (float)acc[i][j][r] * rs[i][r] * s;
    }
  }
}

// Correct-but-slow insurance if ws_size is too small.
__global__ void fallback_kernel(const float* __restrict__ x,
                                const int* __restrict__ wq,
                                const float* __restrict__ s,
                                float* __restrict__ out) {
  size_t idx = (size_t)blockIdx.x * blockDim.x + threadIdx.x;
  int m = (int)(idx / N_DIM), n = (int)(idx % N_DIM);
  const float* xr = x + (size_t)m * K_DIM;
  const int* wr = wq + (size_t)n * K_DIM;
  float acc = 0.f;
  for (int k = 0; k < K_DIM; ++k) acc += xr[k] * (float)wr[k];
  out[idx] = acc * s[n];
}

extern "C" void kernel_launch(void* const* d_in, const int* in_sizes, int n_in,
                              void* d_out, int out_size, void* d_ws, size_t ws_size,
                              hipStream_t stream) {
  const float* x = (const float*)d_in[0];
  const int* wq = (const int*)d_in[1];   // int32 (verified R2)
  const float* sc = (const float*)d_in[2];
  float* out = (float*)d_out;

  const size_t nx = (size_t)M_DIM * K_DIM;   // 33,554,432
  const size_t nw = (size_t)N_DIM * K_DIM;   // 16,777,216
  const size_t off_xq = 32768;               // xs: 8192 floats
  const size_t off_wp = off_xq + nx;
  const size_t need = off_wp + nw;           // ~50.4 MB

  if (ws_size < need) {
    size_t total = (size_t)M_DIM * N_DIM;
    fallback_kernel<<<(int)(total / 256), 256, 0, stream>>>(x, wq, sc, out);
    return;
  }

  float* xs = (float*)d_ws;
  signed char* xq = (signed char*)d_ws + off_xq;
  signed char* wp = (signed char*)d_ws + off_wp;

  quant_x_kernel<<<M_DIM, 256, 0, stream>>>(x, xq, xs);
  pack_w_kernel<<<(int)(nw / 16 / 256), 256, 0, stream>>>(wq, wp);

  gemm_i8<<<(N_DIM / BN) * (M_DIM / BM), 256, 0, stream>>>(xq, wp, xs, sc, out);
}